// Round 12
// baseline (656.202 us; speedup 1.0000x reference)
//
#include <hip/hip_runtime.h>
#include <cstdint>

// ---------------------------------------------------------------------------
// TransformerLayer on MI355X (gfx950)
// Chunked pipeline (chunk C tokens, per-token ws = 9 KiB):
//   once: transpose-cast weights -> bf16 [N][K]
//   per chunk:
//     1. cast x -> bf16 (xb)
//     2. GEMM qkv = xb @ [Wq|Wk|Wv] + bias          (bf16 out, EPI=0)
//     3. attn (per-token 8x8) + residual + LN1 -> y (bf16)
//     4. GEMM h = relu(y @ W1 + b1)                 (bf16 out, EPI=1)
//     5. GEMM zb = h @ W2 + b2 + y                  (bf16 out, EPI=2, aliases qkv)
//     6. LN2(zb) -> out (fp32)
// GEMM (r12): r10 skeleton (256x256, BK=32, 8 waves, quad-buffer 128 KiB,
// counted vmcnt(8), one barrier/tile, r5-proven 0-conflict additive LDS
// swizzle, XCD-bijective block swizzle, setprio) with MFMA switched to
// 32x32x16 bf16: half the MFMA instructions at a higher pipe rate
// (2382 vs 2075 TF ubench), same LDS bytes.
//   A/B frag: row = lane&31, k = (lane>>5)*8 + j  (mirror of verified 16x16)
//   C/D:      col = lane&31, row = (reg&3) + 8*(reg>>2) + 4*(lane>>5)
// ---------------------------------------------------------------------------

typedef __attribute__((ext_vector_type(8))) short bf16x8;
typedef __attribute__((ext_vector_type(4))) float f32x4;
typedef __attribute__((ext_vector_type(16))) float f32x16;
typedef __attribute__((ext_vector_type(8))) unsigned short u16x8;

__device__ __forceinline__ float bf2f(unsigned short u) {
  union { unsigned int i; float f; } v; v.i = ((unsigned int)u) << 16; return v.f;
}
__device__ __forceinline__ unsigned short f2bf(float f) {
  union { float f; unsigned int i; } v; v.f = f;
  unsigned int r = v.i + 0x7FFFu + ((v.i >> 16) & 1u);   // round-nearest-even
  return (unsigned short)(r >> 16);
}

#define GLD16(g, l)                                                         \
  __builtin_amdgcn_global_load_lds(                                         \
      (const __attribute__((address_space(1))) void*)(g),                   \
      (__attribute__((address_space(3))) void*)(l), 16, 0, 0)

// ---------------------------------------------------------------------------
// fp32 -> bf16 cast, 8 elements/thread, vectorized
// ---------------------------------------------------------------------------
__global__ __launch_bounds__(256) void cast_f32_bf16(
    const float* __restrict__ in, ushort* __restrict__ out) {
  const size_t i = (size_t)blockIdx.x * 256 + threadIdx.x;
  const float4* p = (const float4*)in + i * 2;
  float4 a = p[0], b = p[1];
  u16x8 r;
  r[0] = f2bf(a.x); r[1] = f2bf(a.y); r[2] = f2bf(a.z); r[3] = f2bf(a.w);
  r[4] = f2bf(b.x); r[5] = f2bf(b.y); r[6] = f2bf(b.z); r[7] = f2bf(b.w);
  ((u16x8*)out)[i] = r;
}

// ---------------------------------------------------------------------------
// Transpose-cast: W fp32 [K][Nn] row-major -> Wt bf16 [rowoff+Nn][ldt=K]
// ---------------------------------------------------------------------------
__global__ __launch_bounds__(256) void transpose_cast(
    const float* __restrict__ W, ushort* __restrict__ Wt,
    int K, int Nn, int rowoff, int ldt) {
  __shared__ float tile[32][33];
  const int tx = threadIdx.x & 31, ty = threadIdx.x >> 5;  // ty: 0..7
  const int nb = blockIdx.x * 32, kb = blockIdx.y * 32;
#pragma unroll
  for (int s = 0; s < 4; ++s)
    tile[ty + 8 * s][tx] = W[(size_t)(kb + ty + 8 * s) * Nn + nb + tx];
  __syncthreads();
#pragma unroll
  for (int s = 0; s < 4; ++s)
    Wt[(size_t)(rowoff + nb + ty + 8 * s) * ldt + kb + tx] =
        f2bf(tile[tx][ty + 8 * s]);
}

// ---------------------------------------------------------------------------
// bf16 GEMM, C = A[M,K] @ Bt[N,K]^T
// 256x256 tile, BK=32, 8 waves (2M x 4N). Per-wave out 128x64 =
// 4 (M) x 2 (N) tiles of 32x32; 16 MFMA(32x32x16) per K-tile per wave.
// Quad-buffered LDS; stage tile t+3 into buf (t-1)&3 right after tile t's
// top barrier. vmcnt(8) keeps tiles t+1,t+2 in flight. One barrier/tile.
// LDS swizzle (r5-proven): content slot q at row r lives at dest slot
// (q + (r>>1)) & 3; staging source slot = ((tid&3) - ((tid>>3)&3)) & 3.
// EPI 0: +bias(select by n0), bf16 out   (QKV)
// EPI 1: relu(+bias), bf16 out           (FFN1)
// EPI 2: +bias +resid(bf16), bf16 out    (FFN2 -> zb)
// ---------------------------------------------------------------------------
template <int EPI>
__global__ __launch_bounds__(512, 2) void gemm_bt(
    const ushort* __restrict__ A, const ushort* __restrict__ Bt,
    int N, int K, void* __restrict__ Cout,
    const float* __restrict__ bias0, const float* __restrict__ bias1,
    const float* __restrict__ bias2, const ushort* __restrict__ resid) {
  constexpr int BK = 32;
  __shared__ __align__(16) ushort lds[4 * 16384];
  const int tid = threadIdx.x;
  const int wid = tid >> 6, lane = tid & 63;
  const int wm = wid >> 2, wn = wid & 3;
  const int lane31 = lane & 31, kg = lane >> 5;   // frag row / k-group
  const int swr = (lane >> 1) & 3;                // == (row>>1)&3, bases %32

  // ---- XCD-aware bijective block swizzle (m204)
  const int gx = gridDim.x;
  const int nwg = gx * gridDim.y;
  const int orig = blockIdx.y * gx + blockIdx.x;
  const int q8 = nwg >> 3, r8 = nwg & 7;
  const int xcd = orig & 7, loc = orig >> 3;
  const int swz = (xcd < r8) ? (xcd * (q8 + 1) + loc)
                             : (r8 * (q8 + 1) + (xcd - r8) * q8 + loc);
  const size_t m0 = (size_t)(swz / gx) * 256;
  const size_t n0 = (size_t)(swz % gx) * 256;
  const int NT = K / BK;

  // staging (r5 verbatim): thread tid covers granule tid of each 128-row
  // half; linear LDS dest = tid*16B; pre-inverse-swizzled global source
  // slot s = ((tid&3) - ((tid>>3)&3)) & 3.
  const int sgcol = (((tid & 3) - ((tid >> 3) & 3)) & 3) << 3;
  const ushort* a0 = A + (m0 + (tid >> 2)) * (size_t)K + sgcol;
  const ushort* b0 = Bt + (n0 + (tid >> 2)) * (size_t)K + sgcol;
  const size_t rowK = 128 * (size_t)K;
  ushort* ldst = &lds[tid * 8];

  // staging slot sl of tile t: 0 = A rows 0-127, 1 = A rows 128-255,
  // 2 = B rows 0-127, 3 = B rows 128-255 (one 16B gload each).
#define STAGE_SLOT(t, sl)                                                   \
  {                                                                         \
    ushort* d = ldst + ((t) & 3) * 16384 + (sl) * 4096;                     \
    const ushort* g = (((sl) < 2) ? a0 : b0) + (size_t)(t) * BK +           \
                      (((sl) & 1) ? rowK : 0);                              \
    GLD16(g, d);                                                            \
  }

  // reader: frag (row = base + lane31, k-step ks): content slot q = ks*2+kg,
  // dest slot = (q + swr) & 3; addr = row*32 + slot*8 (elems).
  const int arow = wm * 128 + lane31;
  const int brow = wn * 64 + lane31;
#define RD_A(mi, ks)                                                        \
  (*(const bf16x8*)&lA[(arow + (mi) * 32) * 32 +                            \
                       ((((ks) * 2 + kg + swr) & 3) << 3)])
#define RD_B(ni, ks)                                                        \
  (*(const bf16x8*)&lB[(brow + (ni) * 32) * 32 +                            \
                       ((((ks) * 2 + kg + swr) & 3) << 3)])

  f32x16 acc[4][2] = {};

  // prologue: tiles 0,1,2 fully staged (12 loads)
#pragma unroll
  for (int pt = 0; pt < 3; ++pt) {
    STAGE_SLOT(pt, 0); STAGE_SLOT(pt, 1);
    STAGE_SLOT(pt, 2); STAGE_SLOT(pt, 3);
  }

  for (int t = 0; t < NT; ++t) {
    // tile t's 4 loads landed; keep tiles t+1,t+2 (8 loads) in flight
    if (t < NT - 2) {
      asm volatile("s_waitcnt vmcnt(8)" ::: "memory");
    } else if (t == NT - 2) {
      asm volatile("s_waitcnt vmcnt(4)" ::: "memory");
    } else {
      asm volatile("s_waitcnt vmcnt(0)" ::: "memory");
    }
    __builtin_amdgcn_s_barrier();

    const ushort* lA = &lds[(t & 3) * 16384];
    const ushort* lB = lA + 8192;

    // stage tile t+3 first (HBM latency hides under reads+MFMA below)
    if (t + 3 < NT) {
      STAGE_SLOT(t + 3, 0); STAGE_SLOT(t + 3, 1);
      STAGE_SLOT(t + 3, 2); STAGE_SLOT(t + 3, 3);
    }

    // all fragments; compiler schedules lgkmcnt finely, waves drift
    bf16x8 af[4][2], bfr[2][2];
#pragma unroll
    for (int ni = 0; ni < 2; ++ni) {
      bfr[ni][0] = RD_B(ni, 0); bfr[ni][1] = RD_B(ni, 1);
    }
#pragma unroll
    for (int mi = 0; mi < 4; ++mi) {
      af[mi][0] = RD_A(mi, 0); af[mi][1] = RD_A(mi, 1);
    }

    __builtin_amdgcn_s_setprio(1);
#pragma unroll
    for (int mi = 0; mi < 4; ++mi)
#pragma unroll
      for (int ni = 0; ni < 2; ++ni) {
        acc[mi][ni] = __builtin_amdgcn_mfma_f32_32x32x16_bf16(
            af[mi][0], bfr[ni][0], acc[mi][ni], 0, 0, 0);
        acc[mi][ni] = __builtin_amdgcn_mfma_f32_32x32x16_bf16(
            af[mi][1], bfr[ni][1], acc[mi][ni], 0, 0, 0);
      }
    __builtin_amdgcn_s_setprio(0);
  }
#undef STAGE_SLOT
#undef RD_A
#undef RD_B

  // epilogue: D col = lane&31, row = (reg&3) + 8*(reg>>2) + 4*(lane>>5)
  // (m74/m101-verified). rb/j outer, ni inner.
  size_t col[2];
  float bv[2];
#pragma unroll
  for (int ni = 0; ni < 2; ++ni) {
    col[ni] = n0 + wn * 64 + ni * 32 + lane31;
    if (EPI == 0) {
      const float* bp = (n0 < 512) ? bias0 : ((n0 < 1024) ? bias1 : bias2);
      bv[ni] = bp[col[ni] & 511];
    } else {
      bv[ni] = bias0[col[ni]];
    }
  }
#pragma unroll
  for (int mi = 0; mi < 4; ++mi) {
#pragma unroll
    for (int rb = 0; rb < 4; ++rb) {
#pragma unroll
      for (int j = 0; j < 4; ++j) {
        const size_t row = m0 + wm * 128 + mi * 32 + kg * 4 + rb * 8 + j;
#pragma unroll
        for (int ni = 0; ni < 2; ++ni) {
          float v = acc[mi][ni][rb * 4 + j] + bv[ni];
          if (EPI == 0) {
            ((ushort*)Cout)[row * N + col[ni]] = f2bf(v);
          } else if (EPI == 1) {
            ((ushort*)Cout)[row * N + col[ni]] = f2bf(fmaxf(v, 0.f));
          } else {
            v += bf2f(resid[row * N + col[ni]]);
            ((ushort*)Cout)[row * N + col[ni]] = f2bf(v);
          }
        }
      }
    }
  }
}

// ---------------------------------------------------------------------------
// Per-token attention (H=8, HD=64) + residual + LN1 -> y (bf16)
// One wave per token; lane = head-dim element d. Residual from xb (bf16).
// Scores via 6-step transpose-reduce (63 shuffles); softmax in 8-lane groups;
// context via v_readlane broadcast.
// ---------------------------------------------------------------------------
__global__ __launch_bounds__(256) void attn_ln1(
    const ushort* __restrict__ qkv, const ushort* __restrict__ xb,
    const float* __restrict__ g1, const float* __restrict__ b1,
    ushort* __restrict__ y) {
  const int lane = threadIdx.x & 63;
  const size_t t = (size_t)blockIdx.x * 4 + (threadIdx.x >> 6);
  const ushort* base = qkv + t * 1536;
  float qd[8], kd[8], vd[8];
#pragma unroll
  for (int h = 0; h < 8; ++h) {
    qd[h] = bf2f(base[h * 64 + lane]);
    kd[h] = bf2f(base[512 + h * 64 + lane]);
    vd[h] = bf2f(base[1024 + h * 64 + lane]);
  }

  const bool lb0 = lane & 1, lb1 = lane & 2, lb2 = lane & 4;
  const bool lb3 = lane & 8, lb4 = lane & 16, lb5 = lane & 32;

  float c1[32];
#pragma unroll
  for (int f = 0; f < 32; ++f) {
    const int i0 = 2 * f, i1 = 2 * f + 1;
    const float a0 = qd[i0 >> 3] * kd[i0 & 7];
    const float a1 = qd[i1 >> 3] * kd[i1 & 7];
    const float keep = lb0 ? a1 : a0;
    const float send = lb0 ? a0 : a1;
    c1[f] = keep + __shfl_xor(send, 1, 64);
  }
  float c2[16];
#pragma unroll
  for (int f = 0; f < 16; ++f) {
    const float keep = lb1 ? c1[2 * f + 1] : c1[2 * f];
    const float send = lb1 ? c1[2 * f] : c1[2 * f + 1];
    c2[f] = keep + __shfl_xor(send, 2, 64);
  }
  float c3[8];
#pragma unroll
  for (int f = 0; f < 8; ++f) {
    const float keep = lb2 ? c2[2 * f + 1] : c2[2 * f];
    const float send = lb2 ? c2[2 * f] : c2[2 * f + 1];
    c3[f] = keep + __shfl_xor(send, 4, 64);
  }
  float c4[4];
#pragma unroll
  for (int f = 0; f < 4; ++f) {
    const float keep = lb3 ? c3[2 * f + 1] : c3[2 * f];
    const float send = lb3 ? c3[2 * f] : c3[2 * f + 1];
    c4[f] = keep + __shfl_xor(send, 8, 64);
  }
  float c5[2];
#pragma unroll
  for (int f = 0; f < 2; ++f) {
    const float keep = lb4 ? c4[2 * f + 1] : c4[2 * f];
    const float send = lb4 ? c4[2 * f] : c4[2 * f + 1];
    c5[f] = keep + __shfl_xor(send, 16, 64);
  }
  const float keep = lb5 ? c5[1] : c5[0];
  const float send = lb5 ? c5[0] : c5[1];
  const float s = keep + __shfl_xor(send, 32, 64);  // raw score, i = lane

  float mx = s;
  mx = fmaxf(mx, __shfl_xor(mx, 1, 64));
  mx = fmaxf(mx, __shfl_xor(mx, 2, 64));
  mx = fmaxf(mx, __shfl_xor(mx, 4, 64));
  const float e = __expf((s - mx) * 0.125f);
  float sum = e;
  sum += __shfl_xor(sum, 1, 64);
  sum += __shfl_xor(sum, 2, 64);
  sum += __shfl_xor(sum, 4, 64);
  const float a = e * __builtin_amdgcn_rcpf(sum);

  const int ai = __float_as_int(a);
  float r[8];
#pragma unroll
  for (int h = 0; h < 8; ++h) {
    float c = 0.f;
#pragma unroll
    for (int g = 0; g < 8; ++g) {
      const float w = __int_as_float(__builtin_amdgcn_readlane(ai, h * 8 + g));
      c = fmaf(w, vd[g], c);
    }
    r[h] = bf2f(xb[t * 512 + h * 64 + lane]) + c;
  }

  float sm = 0.f, sq = 0.f;
#pragma unroll
  for (int h = 0; h < 8; ++h) { sm += r[h]; sq += r[h] * r[h]; }
#pragma unroll
  for (int m = 1; m < 64; m <<= 1) {
    sm += __shfl_xor(sm, m, 64);
    sq += __shfl_xor(sq, m, 64);
  }
  const float mu = sm * (1.f / 512.f);
  const float var = sq * (1.f / 512.f) - mu * mu;
  const float rs = rsqrtf(var + 1e-5f);
#pragma unroll
  for (int h = 0; h < 8; ++h) {
    const int d = h * 64 + lane;
    y[t * 512 + d] = f2bf((r[h] - mu) * rs * g1[d] + b1[d]);
  }
}

// ---------------------------------------------------------------------------
// LN2(zb bf16) -> out fp32. One wave per token; lane owns 8 contiguous elems.
// ---------------------------------------------------------------------------
__global__ __launch_bounds__(256) void ln_out(
    const ushort* __restrict__ zb, const float* __restrict__ g2,
    const float* __restrict__ b2, float* __restrict__ out) {
  const int lane = threadIdx.x & 63;
  const size_t t = (size_t)blockIdx.x * 4 + (threadIdx.x >> 6);
  const u16x8 v = ((const u16x8*)(zb + t * 512))[lane];
  float r[8];
  float sm = 0.f, sq = 0.f;
#pragma unroll
  for (int j = 0; j < 8; ++j) {
    r[j] = bf2f(v[j]);
    sm += r[j];
    sq += r[j] * r[j];
  }
#pragma unroll
  for (int m = 1; m < 64; m <<= 1) {
    sm += __shfl_xor(sm, m, 64);
    sq += __shfl_xor(sq, m, 64);
  }
  const float mu = sm * (1.f / 512.f);
  const float rs = rsqrtf(sq * (1.f / 512.f) - mu * mu + 1e-5f);
  const int d0 = lane * 8;
  const float4 ga = *(const float4*)(g2 + d0);
  const float4 gb = *(const float4*)(g2 + d0 + 4);
  const float4 ba = *(const float4*)(b2 + d0);
  const float4 bb = *(const float4*)(b2 + d0 + 4);
  float4 oa, ob;
  oa.x = (r[0] - mu) * rs * ga.x + ba.x;
  oa.y = (r[1] - mu) * rs * ga.y + ba.y;
  oa.z = (r[2] - mu) * rs * ga.z + ba.z;
  oa.w = (r[3] - mu) * rs * ga.w + ba.w;
  ob.x = (r[4] - mu) * rs * gb.x + bb.x;
  ob.y = (r[5] - mu) * rs * gb.y + bb.y;
  ob.z = (r[6] - mu) * rs * gb.z + bb.z;
  ob.w = (r[7] - mu) * rs * gb.w + bb.w;
  float* o = out + t * 512 + d0;
  *(float4*)o = oa;
  *(float4*)(o + 4) = ob;
}

// ---------------------------------------------------------------------------
extern "C" void kernel_launch(void* const* d_in, const int* in_sizes, int n_in,
                              void* d_out, int out_size, void* d_ws,
                              size_t ws_size, hipStream_t stream) {
  const float* x    = (const float*)d_in[0];
  const float* Wq   = (const float*)d_in[1];
  const float* bq   = (const float*)d_in[2];
  const float* Wk   = (const float*)d_in[3];
  const float* bk   = (const float*)d_in[4];
  const float* Wv   = (const float*)d_in[5];
  const float* bv   = (const float*)d_in[6];
  const float* ln1g = (const float*)d_in[7];
  const float* ln1b = (const float*)d_in[8];
  const float* W1   = (const float*)d_in[9];
  const float* b1   = (const float*)d_in[10];
  const float* W2   = (const float*)d_in[11];
  const float* b2   = (const float*)d_in[12];
  const float* ln2g = (const float*)d_in[13];
  const float* ln2b = (const float*)d_in[14];
  float* out = (float*)d_out;

  const int Ntok = in_sizes[0] / 512;  // 65536

  // ---- workspace layout: weights once, then chunk buffers (9 KiB/token)
  char* ws = (char*)d_ws;
  ushort* Wqkvt = (ushort*)ws;                       // [1536][512]
  ushort* W1t   = Wqkvt + (size_t)1536 * 512;        // [2048][512]
  ushort* W2t   = W1t + (size_t)2048 * 512;          // [512][2048]
  const size_t woff = ((size_t)1536 * 512 + (size_t)2048 * 512 +
                       (size_t)512 * 2048) * 2;      // 5.5 MiB

  size_t avail = (ws_size > woff) ? (ws_size - woff) : 0;
  long long Cll = (long long)(avail / 9216);
  Cll = (Cll / 256) * 256;
  if (Cll > 32768) Cll = 32768;
  if (Cll > Ntok) Cll = Ntok;
  if (Cll < 256) Cll = 256;
  const int C = (int)Cll;

  char* cb = ws + woff;
  ushort* xb  = (ushort*)cb;                          // [C][512] bf16
  ushort* y   = xb + (size_t)C * 512;                 // [C][512] bf16
  ushort* qkv = y + (size_t)C * 512;                  // [C][1536] bf16
  ushort* hb  = qkv + (size_t)C * 1536;               // [C][2048] bf16
  ushort* zb  = qkv;                                  // [C][512] bf16 (aliases qkv)

  // ---- weight transposes (once)
  transpose_cast<<<dim3(16, 16), dim3(256), 0, stream>>>(Wq, Wqkvt, 512, 512, 0, 512);
  transpose_cast<<<dim3(16, 16), dim3(256), 0, stream>>>(Wk, Wqkvt, 512, 512, 512, 512);
  transpose_cast<<<dim3(16, 16), dim3(256), 0, stream>>>(Wv, Wqkvt, 512, 512, 1024, 512);
  transpose_cast<<<dim3(64, 16), dim3(256), 0, stream>>>(W1, W1t, 512, 2048, 0, 512);
  transpose_cast<<<dim3(16, 64), dim3(256), 0, stream>>>(W2, W2t, 2048, 512, 0, 2048);

  // ---- chunked pipeline
  for (int t0 = 0; t0 < Ntok; t0 += C) {
    const int Cc = (Ntok - t0 < C) ? (Ntok - t0) : C;   // multiple of 256
    const float* xc = x + (size_t)t0 * 512;

    cast_f32_bf16<<<dim3((Cc * 512) / 2048), dim3(256), 0, stream>>>(xc, xb);

    gemm_bt<0><<<dim3(1536 / 256, Cc / 256), dim3(512), 0, stream>>>(
        xb, Wqkvt, 1536, 512, qkv, bq, bk, bv, nullptr);

    attn_ln1<<<dim3(Cc / 4), dim3(256), 0, stream>>>(qkv, xb, ln1g, ln1b, y);

    gemm_bt<1><<<dim3(2048 / 256, Cc / 256), dim3(512), 0, stream>>>(
        y, W1t, 2048, 512, hb, b1, nullptr, nullptr, nullptr);

    gemm_bt<2><<<dim3(512 / 256, Cc / 256), dim3(512), 0, stream>>>(
        hb, W2t, 512, 2048, zb, b2, nullptr, nullptr, y);

    ln_out<<<dim3(Cc / 4), dim3(256), 0, stream>>>(
        zb, ln2g, ln2b, out + (size_t)t0 * 512);
  }
}

// Round 13
// 652.833 us; speedup vs baseline: 1.0052x; 1.0052x over previous
//
#include <hip/hip_runtime.h>
#include <cstdint>

// ---------------------------------------------------------------------------
// TransformerLayer on MI355X (gfx950)
// Chunked pipeline (chunk C tokens, per-token ws = 9 KiB):
//   once: transpose-cast weights -> bf16 [N][K]
//   per chunk:
//     1. cast x -> bf16 (xb)
//     2. GEMM qkv = xb @ [Wq|Wk|Wv] + bias          (bf16 out, EPI=0)
//     3. attn (per-token 8x8) + residual + LN1 -> y (bf16)
//     4. GEMM h = relu(y @ W1 + b1)                 (bf16 out, EPI=1)
//     5. GEMM zb = h @ W2 + b2 + y                  (bf16 out, EPI=2, aliases qkv)
//     6. LN2(zb) -> out (fp32)
// GEMM (r13): r10 skeleton (256x256, BK=32, 8 waves, 16x16x32 MFMA,
// r5-proven 0-conflict additive LDS swizzle, XCD-bijective block swizzle,
// one barrier/tile, setprio) with LDS cut to a DOUBLE buffer (64 KiB) ->
// 2 blocks/CU. Thesis (m114): inter-block wave overlap absorbs the
// tile-top vmcnt+barrier stall that a single resident block exposes.
// Prefetch depth 1 (stage t+1 during t; loads get a full tile-compute
// window ~3.7k cyc >> HBM latency before the vmcnt(0) at top of t+1).
// ---------------------------------------------------------------------------

typedef __attribute__((ext_vector_type(8))) short bf16x8;
typedef __attribute__((ext_vector_type(4))) float f32x4;
typedef __attribute__((ext_vector_type(8))) unsigned short u16x8;

__device__ __forceinline__ float bf2f(unsigned short u) {
  union { unsigned int i; float f; } v; v.i = ((unsigned int)u) << 16; return v.f;
}
__device__ __forceinline__ unsigned short f2bf(float f) {
  union { float f; unsigned int i; } v; v.f = f;
  unsigned int r = v.i + 0x7FFFu + ((v.i >> 16) & 1u);   // round-nearest-even
  return (unsigned short)(r >> 16);
}

#define GLD16(g, l)                                                         \
  __builtin_amdgcn_global_load_lds(                                         \
      (const __attribute__((address_space(1))) void*)(g),                   \
      (__attribute__((address_space(3))) void*)(l), 16, 0, 0)

// ---------------------------------------------------------------------------
// fp32 -> bf16 cast, 8 elements/thread, vectorized
// ---------------------------------------------------------------------------
__global__ __launch_bounds__(256) void cast_f32_bf16(
    const float* __restrict__ in, ushort* __restrict__ out) {
  const size_t i = (size_t)blockIdx.x * 256 + threadIdx.x;
  const float4* p = (const float4*)in + i * 2;
  float4 a = p[0], b = p[1];
  u16x8 r;
  r[0] = f2bf(a.x); r[1] = f2bf(a.y); r[2] = f2bf(a.z); r[3] = f2bf(a.w);
  r[4] = f2bf(b.x); r[5] = f2bf(b.y); r[6] = f2bf(b.z); r[7] = f2bf(b.w);
  ((u16x8*)out)[i] = r;
}

// ---------------------------------------------------------------------------
// Transpose-cast: W fp32 [K][Nn] row-major -> Wt bf16 [rowoff+Nn][ldt=K]
// ---------------------------------------------------------------------------
__global__ __launch_bounds__(256) void transpose_cast(
    const float* __restrict__ W, ushort* __restrict__ Wt,
    int K, int Nn, int rowoff, int ldt) {
  __shared__ float tile[32][33];
  const int tx = threadIdx.x & 31, ty = threadIdx.x >> 5;  // ty: 0..7
  const int nb = blockIdx.x * 32, kb = blockIdx.y * 32;
#pragma unroll
  for (int s = 0; s < 4; ++s)
    tile[ty + 8 * s][tx] = W[(size_t)(kb + ty + 8 * s) * Nn + nb + tx];
  __syncthreads();
#pragma unroll
  for (int s = 0; s < 4; ++s)
    Wt[(size_t)(rowoff + nb + ty + 8 * s) * ldt + kb + tx] =
        f2bf(tile[tx][ty + 8 * s]);
}

// ---------------------------------------------------------------------------
// bf16 GEMM, C = A[M,K] @ Bt[N,K]^T
// 256x256 tile, BK=32, 8 waves (2M x 4N), per-wave out 128x64 (8x4 frags
// of 16x16x32). DOUBLE-buffered LDS (2 x 32 KiB = 64 KiB -> 2 blocks/CU).
// Stage tile t+1 into buf (t+1)&1 right after tile t's top barrier (that
// buffer's readers, tile t-1, all completed before the barrier). vmcnt(0)
// at tile top: t's 4 loads were issued one full tile-compute ago.
// LDS swizzle (r5-proven 0 conflicts): content slot q at row r lives at
// dest slot (q + (r>>1)) & 3; staging source slot = ((tid&3)-((tid>>3)&3))&3.
// EPI 0: +bias(select by n0), bf16 out   (QKV)
// EPI 1: relu(+bias), bf16 out           (FFN1)
// EPI 2: +bias +resid(bf16), bf16 out    (FFN2 -> zb)
// ---------------------------------------------------------------------------
template <int EPI>
__global__ __launch_bounds__(512, 2) void gemm_bt(
    const ushort* __restrict__ A, const ushort* __restrict__ Bt,
    int N, int K, void* __restrict__ Cout,
    const float* __restrict__ bias0, const float* __restrict__ bias1,
    const float* __restrict__ bias2, const ushort* __restrict__ resid) {
  constexpr int BK = 32;
  __shared__ __align__(16) ushort lds[2 * 16384];
  const int tid = threadIdx.x;
  const int wid = tid >> 6, lane = tid & 63;
  const int wm = wid >> 2, wn = wid & 3;

  // ---- XCD-aware bijective block swizzle (m204)
  const int gx = gridDim.x;
  const int nwg = gx * gridDim.y;
  const int orig = blockIdx.y * gx + blockIdx.x;
  const int q8 = nwg >> 3, r8 = nwg & 7;
  const int xcd = orig & 7, loc = orig >> 3;
  const int swz = (xcd < r8) ? (xcd * (q8 + 1) + loc)
                             : (r8 * (q8 + 1) + (xcd - r8) * q8 + loc);
  const size_t m0 = (size_t)(swz / gx) * 256;
  const size_t n0 = (size_t)(swz % gx) * 256;
  const int NT = K / BK;

  // staging (r5 verbatim): thread tid covers granule tid of each 128-row
  // half; linear LDS dest = tid*16B; pre-inverse-swizzled global source
  // slot s = ((tid&3) - ((tid>>3)&3)) & 3.
  const int sgcol = (((tid & 3) - ((tid >> 3) & 3)) & 3) << 3;
  const ushort* a0 = A + (m0 + (tid >> 2)) * (size_t)K + sgcol;
  const ushort* b0 = Bt + (n0 + (tid >> 2)) * (size_t)K + sgcol;
  const size_t rowK = 128 * (size_t)K;
  ushort* ldst = &lds[tid * 8];

  // staging slot sl of tile t: 0 = A rows 0-127, 1 = A rows 128-255,
  // 2 = B rows 0-127, 3 = B rows 128-255 (one 16B gload each).
#define STAGE_SLOT(t, sl)                                                   \
  {                                                                         \
    ushort* d = ldst + ((t) & 1) * 16384 + (sl) * 4096;                     \
    const ushort* g = (((sl) < 2) ? a0 : b0) + (size_t)(t) * BK +           \
                      (((sl) & 1) ? rowK : 0);                              \
    GLD16(g, d);                                                            \
  }

  // reader (r5 verbatim): frag (row = base + lane&15, content slot
  // q = lane>>4) lives at slot' = (q + (row>>1)) & 3; (row>>1)&3 ==
  // (lane>>1)&3 since bases are multiples of 16.
  const int cswz = ((((lane >> 4) + ((lane >> 1) & 3)) & 3) << 3);
  const int arow = wm * 128 + (lane & 15);
  const int brow = wn * 64 + (lane & 15);

  f32x4 acc[8][4] = {};

  // prologue: tile 0 staged (4 loads)
  STAGE_SLOT(0, 0); STAGE_SLOT(0, 1);
  STAGE_SLOT(0, 2); STAGE_SLOT(0, 3);

  for (int t = 0; t < NT; ++t) {
    // tile t's 4 loads (issued one full tile-compute ago) must be done
    asm volatile("s_waitcnt vmcnt(0)" ::: "memory");
    __builtin_amdgcn_s_barrier();

    const ushort* lA = &lds[(t & 1) * 16384];
    const ushort* lB = lA + 8192;

    // stage tile t+1 (its buffer's readers finished before this barrier);
    // HBM latency hides under this tile's reads+MFMA.
    if (t + 1 < NT) {
      STAGE_SLOT(t + 1, 0); STAGE_SLOT(t + 1, 1);
      STAGE_SLOT(t + 1, 2); STAGE_SLOT(t + 1, 3);
    }

    // all fragments; compiler schedules lgkmcnt finely, waves drift
    bf16x8 bfr[4], af[8];
#pragma unroll
    for (int ni = 0; ni < 4; ++ni)
      bfr[ni] = *(const bf16x8*)&lB[(brow + ni * 16) * 32 + cswz];
#pragma unroll
    for (int mi = 0; mi < 8; ++mi)
      af[mi] = *(const bf16x8*)&lA[(arow + mi * 16) * 32 + cswz];

    __builtin_amdgcn_s_setprio(1);
#pragma unroll
    for (int mi = 0; mi < 8; ++mi)
#pragma unroll
      for (int ni = 0; ni < 4; ++ni)
        acc[mi][ni] = __builtin_amdgcn_mfma_f32_16x16x32_bf16(
            af[mi], bfr[ni], acc[mi][ni], 0, 0, 0);
    __builtin_amdgcn_s_setprio(0);
  }
#undef STAGE_SLOT

  // epilogue: D col = lane&15, row = (lane>>4)*4 + j (m89-verified).
  // mi/j outer, ni inner (row's segments issued back-to-back).
  const int lm = lane & 15, lq = lane >> 4;
  size_t col[4];
  float bv[4];
#pragma unroll
  for (int ni = 0; ni < 4; ++ni) {
    col[ni] = n0 + wn * 64 + ni * 16 + lm;
    if (EPI == 0) {
      const float* bp = (n0 < 512) ? bias0 : ((n0 < 1024) ? bias1 : bias2);
      bv[ni] = bp[col[ni] & 511];
    } else {
      bv[ni] = bias0[col[ni]];
    }
  }
#pragma unroll
  for (int mi = 0; mi < 8; ++mi) {
#pragma unroll
    for (int j = 0; j < 4; ++j) {
      const size_t row = m0 + wm * 128 + mi * 16 + lq * 4 + j;
#pragma unroll
      for (int ni = 0; ni < 4; ++ni) {
        float v = acc[mi][ni][j] + bv[ni];
        if (EPI == 0) {
          ((ushort*)Cout)[row * N + col[ni]] = f2bf(v);
        } else if (EPI == 1) {
          ((ushort*)Cout)[row * N + col[ni]] = f2bf(fmaxf(v, 0.f));
        } else {
          v += bf2f(resid[row * N + col[ni]]);
          ((ushort*)Cout)[row * N + col[ni]] = f2bf(v);
        }
      }
    }
  }
}

// ---------------------------------------------------------------------------
// Per-token attention (H=8, HD=64) + residual + LN1 -> y (bf16)
// One wave per token; lane = head-dim element d. Residual from xb (bf16).
// Scores via 6-step transpose-reduce (63 shuffles); softmax in 8-lane groups;
// context via v_readlane broadcast.
// ---------------------------------------------------------------------------
__global__ __launch_bounds__(256) void attn_ln1(
    const ushort* __restrict__ qkv, const ushort* __restrict__ xb,
    const float* __restrict__ g1, const float* __restrict__ b1,
    ushort* __restrict__ y) {
  const int lane = threadIdx.x & 63;
  const size_t t = (size_t)blockIdx.x * 4 + (threadIdx.x >> 6);
  const ushort* base = qkv + t * 1536;
  float qd[8], kd[8], vd[8];
#pragma unroll
  for (int h = 0; h < 8; ++h) {
    qd[h] = bf2f(base[h * 64 + lane]);
    kd[h] = bf2f(base[512 + h * 64 + lane]);
    vd[h] = bf2f(base[1024 + h * 64 + lane]);
  }

  const bool lb0 = lane & 1, lb1 = lane & 2, lb2 = lane & 4;
  const bool lb3 = lane & 8, lb4 = lane & 16, lb5 = lane & 32;

  float c1[32];
#pragma unroll
  for (int f = 0; f < 32; ++f) {
    const int i0 = 2 * f, i1 = 2 * f + 1;
    const float a0 = qd[i0 >> 3] * kd[i0 & 7];
    const float a1 = qd[i1 >> 3] * kd[i1 & 7];
    const float keep = lb0 ? a1 : a0;
    const float send = lb0 ? a0 : a1;
    c1[f] = keep + __shfl_xor(send, 1, 64);
  }
  float c2[16];
#pragma unroll
  for (int f = 0; f < 16; ++f) {
    const float keep = lb1 ? c1[2 * f + 1] : c1[2 * f];
    const float send = lb1 ? c1[2 * f] : c1[2 * f + 1];
    c2[f] = keep + __shfl_xor(send, 2, 64);
  }
  float c3[8];
#pragma unroll
  for (int f = 0; f < 8; ++f) {
    const float keep = lb2 ? c2[2 * f + 1] : c2[2 * f];
    const float send = lb2 ? c2[2 * f] : c2[2 * f + 1];
    c3[f] = keep + __shfl_xor(send, 4, 64);
  }
  float c4[4];
#pragma unroll
  for (int f = 0; f < 4; ++f) {
    const float keep = lb3 ? c3[2 * f + 1] : c3[2 * f];
    const float send = lb3 ? c3[2 * f] : c3[2 * f + 1];
    c4[f] = keep + __shfl_xor(send, 8, 64);
  }
  float c5[2];
#pragma unroll
  for (int f = 0; f < 2; ++f) {
    const float keep = lb4 ? c4[2 * f + 1] : c4[2 * f];
    const float send = lb4 ? c4[2 * f] : c4[2 * f + 1];
    c5[f] = keep + __shfl_xor(send, 16, 64);
  }
  const float keep = lb5 ? c5[1] : c5[0];
  const float send = lb5 ? c5[0] : c5[1];
  const float s = keep + __shfl_xor(send, 32, 64);  // raw score, i = lane

  float mx = s;
  mx = fmaxf(mx, __shfl_xor(mx, 1, 64));
  mx = fmaxf(mx, __shfl_xor(mx, 2, 64));
  mx = fmaxf(mx, __shfl_xor(mx, 4, 64));
  const float e = __expf((s - mx) * 0.125f);
  float sum = e;
  sum += __shfl_xor(sum, 1, 64);
  sum += __shfl_xor(sum, 2, 64);
  sum += __shfl_xor(sum, 4, 64);
  const float a = e * __builtin_amdgcn_rcpf(sum);

  const int ai = __float_as_int(a);
  float r[8];
#pragma unroll
  for (int h = 0; h < 8; ++h) {
    float c = 0.f;
#pragma unroll
    for (int g = 0; g < 8; ++g) {
      const float w = __int_as_float(__builtin_amdgcn_readlane(ai, h * 8 + g));
      c = fmaf(w, vd[g], c);
    }
    r[h] = bf2f(xb[t * 512 + h * 64 + lane]) + c;
  }

  float sm = 0.f, sq = 0.f;
#pragma unroll
  for (int h = 0; h < 8; ++h) { sm += r[h]; sq += r[h] * r[h]; }
#pragma unroll
  for (int m = 1; m < 64; m <<= 1) {
    sm += __shfl_xor(sm, m, 64);
    sq += __shfl_xor(sq, m, 64);
  }
  const float mu = sm * (1.f / 512.f);
  const float var = sq * (1.f / 512.f) - mu * mu;
  const float rs = rsqrtf(var + 1e-5f);
#pragma unroll
  for (int h = 0; h < 8; ++h) {
    const int d = h * 64 + lane;
    y[t * 512 + d] = f2bf((r[h] - mu) * rs * g1[d] + b1[d]);
  }
}

// ---------------------------------------------------------------------------
// LN2(zb bf16) -> out fp32. One wave per token; lane owns 8 contiguous elems.
// ---------------------------------------------------------------------------
__global__ __launch_bounds__(256) void ln_out(
    const ushort* __restrict__ zb, const float* __restrict__ g2,
    const float* __restrict__ b2, float* __restrict__ out) {
  const int lane = threadIdx.x & 63;
  const size_t t = (size_t)blockIdx.x * 4 + (threadIdx.x >> 6);
  const u16x8 v = ((const u16x8*)(zb + t * 512))[lane];
  float r[8];
  float sm = 0.f, sq = 0.f;
#pragma unroll
  for (int j = 0; j < 8; ++j) {
    r[j] = bf2f(v[j]);
    sm += r[j];
    sq += r[j] * r[j];
  }
#pragma unroll
  for (int m = 1; m < 64; m <<= 1) {
    sm += __shfl_xor(sm, m, 64);
    sq += __shfl_xor(sq, m, 64);
  }
  const float mu = sm * (1.f / 512.f);
  const float rs = rsqrtf(sq * (1.f / 512.f) - mu * mu + 1e-5f);
  const int d0 = lane * 8;
  const float4 ga = *(const float4*)(g2 + d0);
  const float4 gb = *(const float4*)(g2 + d0 + 4);
  const float4 ba = *(const float4*)(b2 + d0);
  const float4 bb = *(const float4*)(b2 + d0 + 4);
  float4 oa, ob;
  oa.x = (r[0] - mu) * rs * ga.x + ba.x;
  oa.y = (r[1] - mu) * rs * ga.y + ba.y;
  oa.z = (r[2] - mu) * rs * ga.z + ba.z;
  oa.w = (r[3] - mu) * rs * ga.w + ba.w;
  ob.x = (r[4] - mu) * rs * gb.x + bb.x;
  ob.y = (r[5] - mu) * rs * gb.y + bb.y;
  ob.z = (r[6] - mu) * rs * gb.z + bb.z;
  ob.w = (r[7] - mu) * rs * gb.w + bb.w;
  float* o = out + t * 512 + d0;
  *(float4*)o = oa;
  *(float4*)(o + 4) = ob;
}

// ---------------------------------------------------------------------------
extern "C" void kernel_launch(void* const* d_in, const int* in_sizes, int n_in,
                              void* d_out, int out_size, void* d_ws,
                              size_t ws_size, hipStream_t stream) {
  const float* x    = (const float*)d_in[0];
  const float* Wq   = (const float*)d_in[1];
  const float* bq   = (const float*)d_in[2];
  const float* Wk   = (const float*)d_in[3];
  const float* bk   = (const float*)d_in[4];
  const float* Wv   = (const float*)d_in[5];
  const float* bv   = (const float*)d_in[6];
  const float* ln1g = (const float*)d_in[7];
  const float* ln1b = (const float*)d_in[8];
  const float* W1   = (const float*)d_in[9];
  const float* b1   = (const float*)d_in[10];
  const float* W2   = (const float*)d_in[11];
  const float* b2   = (const float*)d_in[12];
  const float* ln2g = (const float*)d_in[13];
  const float* ln2b = (const float*)d_in[14];
  float* out = (float*)d_out;

  const int Ntok = in_sizes[0] / 512;  // 65536

  // ---- workspace layout: weights once, then chunk buffers (9 KiB/token)
  char* ws = (char*)d_ws;
  ushort* Wqkvt = (ushort*)ws;                       // [1536][512]
  ushort* W1t   = Wqkvt + (size_t)1536 * 512;        // [2048][512]
  ushort* W2t   = W1t + (size_t)2048 * 512;          // [512][2048]
  const size_t woff = ((size_t)1536 * 512 + (size_t)2048 * 512 +
                       (size_t)512 * 2048) * 2;      // 5.5 MiB

  size_t avail = (ws_size > woff) ? (ws_size - woff) : 0;
  long long Cll = (long long)(avail / 9216);
  Cll = (Cll / 256) * 256;
  if (Cll > 32768) Cll = 32768;
  if (Cll > Ntok) Cll = Ntok;
  if (Cll < 256) Cll = 256;
  const int C = (int)Cll;

  char* cb = ws + woff;
  ushort* xb  = (ushort*)cb;                          // [C][512] bf16
  ushort* y   = xb + (size_t)C * 512;                 // [C][512] bf16
  ushort* qkv = y + (size_t)C * 512;                  // [C][1536] bf16
  ushort* hb  = qkv + (size_t)C * 1536;               // [C][2048] bf16
  ushort* zb  = qkv;                                  // [C][512] bf16 (aliases qkv)

  // ---- weight transposes (once)
  transpose_cast<<<dim3(16, 16), dim3(256), 0, stream>>>(Wq, Wqkvt, 512, 512, 0, 512);
  transpose_cast<<<dim3(16, 16), dim3(256), 0, stream>>>(Wk, Wqkvt, 512, 512, 512, 512);
  transpose_cast<<<dim3(16, 16), dim3(256), 0, stream>>>(Wv, Wqkvt, 512, 512, 1024, 512);
  transpose_cast<<<dim3(64, 16), dim3(256), 0, stream>>>(W1, W1t, 512, 2048, 0, 512);
  transpose_cast<<<dim3(16, 64), dim3(256), 0, stream>>>(W2, W2t, 2048, 512, 0, 2048);

  // ---- chunked pipeline
  for (int t0 = 0; t0 < Ntok; t0 += C) {
    const int Cc = (Ntok - t0 < C) ? (Ntok - t0) : C;   // multiple of 256
    const float* xc = x + (size_t)t0 * 512;

    cast_f32_bf16<<<dim3((Cc * 512) / 2048), dim3(256), 0, stream>>>(xc, xb);

    gemm_bt<0><<<dim3(1536 / 256, Cc / 256), dim3(512), 0, stream>>>(
        xb, Wqkvt, 1536, 512, qkv, bq, bk, bv, nullptr);

    attn_ln1<<<dim3(Cc / 4), dim3(256), 0, stream>>>(qkv, xb, ln1g, ln1b, y);

    gemm_bt<1><<<dim3(2048 / 256, Cc / 256), dim3(512), 0, stream>>>(
        y, W1t, 2048, 512, hb, b1, nullptr, nullptr, nullptr);

    gemm_bt<2><<<dim3(512 / 256, Cc / 256), dim3(512), 0, stream>>>(
        hb, W2t, 512, 2048, zb, b2, nullptr, nullptr, y);

    ln_out<<<dim3(Cc / 4), dim3(256), 0, stream>>>(
        zb, ln2g, ln2b, out + (size_t)t0 * 512);
  }
}

// Round 14
// 649.810 us; speedup vs baseline: 1.0098x; 1.0047x over previous
//
#include <hip/hip_runtime.h>
#include <cstdint>

// ---------------------------------------------------------------------------
// TransformerLayer on MI355X (gfx950)
// Single-chunk pipeline (C tokens, 6 KiB/token via aliasing; falls back to
// chunks if ws is small):
//   once: transpose-cast weights -> bf16 [N][K]
//   1. cast x -> bf16 (xb)
//   2. GEMM qkv = xb @ [Wq|Wk|Wv] + bias          (bf16 out, EPI=0)
//   3. attn (per-token 8x8) + residual + LN1 -> y (bf16)
//   4. GEMM h = relu(y @ W1 + b1)                 (bf16 out, EPI=1; hb ALIASES
//      the dead [xb|qkv] region)
//   5. GEMM zb = h @ W2 + b2 + y                  (bf16 out, EPI=2)
//   6. LN2(zb) -> out (fp32)
// GEMM (r14 = r10, best measured): 256x256, BK=32, 8 waves, quad-buffered
// LDS (128 KiB), counted vmcnt(8) (2 tiles in flight), one barrier/tile,
// r5-proven 0-conflict additive LDS swizzle, XCD-bijective block swizzle,
// setprio around MFMA.
// ---------------------------------------------------------------------------

typedef __attribute__((ext_vector_type(8))) short bf16x8;
typedef __attribute__((ext_vector_type(4))) float f32x4;
typedef __attribute__((ext_vector_type(8))) unsigned short u16x8;

__device__ __forceinline__ float bf2f(unsigned short u) {
  union { unsigned int i; float f; } v; v.i = ((unsigned int)u) << 16; return v.f;
}
__device__ __forceinline__ unsigned short f2bf(float f) {
  union { float f; unsigned int i; } v; v.f = f;
  unsigned int r = v.i + 0x7FFFu + ((v.i >> 16) & 1u);   // round-nearest-even
  return (unsigned short)(r >> 16);
}

#define GLD16(g, l)                                                         \
  __builtin_amdgcn_global_load_lds(                                         \
      (const __attribute__((address_space(1))) void*)(g),                   \
      (__attribute__((address_space(3))) void*)(l), 16, 0, 0)

// ---------------------------------------------------------------------------
// fp32 -> bf16 cast, 8 elements/thread, vectorized
// ---------------------------------------------------------------------------
__global__ __launch_bounds__(256) void cast_f32_bf16(
    const float* __restrict__ in, ushort* __restrict__ out) {
  const size_t i = (size_t)blockIdx.x * 256 + threadIdx.x;
  const float4* p = (const float4*)in + i * 2;
  float4 a = p[0], b = p[1];
  u16x8 r;
  r[0] = f2bf(a.x); r[1] = f2bf(a.y); r[2] = f2bf(a.z); r[3] = f2bf(a.w);
  r[4] = f2bf(b.x); r[5] = f2bf(b.y); r[6] = f2bf(b.z); r[7] = f2bf(b.w);
  ((u16x8*)out)[i] = r;
}

// ---------------------------------------------------------------------------
// Transpose-cast: W fp32 [K][Nn] row-major -> Wt bf16 [rowoff+Nn][ldt=K]
// ---------------------------------------------------------------------------
__global__ __launch_bounds__(256) void transpose_cast(
    const float* __restrict__ W, ushort* __restrict__ Wt,
    int K, int Nn, int rowoff, int ldt) {
  __shared__ float tile[32][33];
  const int tx = threadIdx.x & 31, ty = threadIdx.x >> 5;  // ty: 0..7
  const int nb = blockIdx.x * 32, kb = blockIdx.y * 32;
#pragma unroll
  for (int s = 0; s < 4; ++s)
    tile[ty + 8 * s][tx] = W[(size_t)(kb + ty + 8 * s) * Nn + nb + tx];
  __syncthreads();
#pragma unroll
  for (int s = 0; s < 4; ++s)
    Wt[(size_t)(rowoff + nb + ty + 8 * s) * ldt + kb + tx] =
        f2bf(tile[tx][ty + 8 * s]);
}

// ---------------------------------------------------------------------------
// bf16 GEMM, C = A[M,K] @ Bt[N,K]^T   (r10 verbatim — best measured)
// 256x256 tile, BK=32, 8 waves (2M x 4N), per-wave out 128x64 (8x4 frags).
// Quad-buffered LDS; stage tile t+3 into buf (t-1)&3 right after tile t's
// top barrier. vmcnt(8) keeps tiles t+1,t+2 in flight. One barrier/tile.
// LDS swizzle (r5-proven 0 conflicts): content slot q at row r lives at
// dest slot (q + (r>>1)) & 3; staging source slot = ((tid&3)-((tid>>3)&3))&3.
// EPI 0: +bias(select by n0), bf16 out   (QKV)
// EPI 1: relu(+bias), bf16 out           (FFN1)
// EPI 2: +bias +resid(bf16), bf16 out    (FFN2 -> zb)
// ---------------------------------------------------------------------------
template <int EPI>
__global__ __launch_bounds__(512, 2) void gemm_bt(
    const ushort* __restrict__ A, const ushort* __restrict__ Bt,
    int N, int K, void* __restrict__ Cout,
    const float* __restrict__ bias0, const float* __restrict__ bias1,
    const float* __restrict__ bias2, const ushort* __restrict__ resid) {
  constexpr int BK = 32;
  __shared__ __align__(16) ushort lds[4 * 16384];
  const int tid = threadIdx.x;
  const int wid = tid >> 6, lane = tid & 63;
  const int wm = wid >> 2, wn = wid & 3;

  // ---- XCD-aware bijective block swizzle (m204)
  const int gx = gridDim.x;
  const int nwg = gx * gridDim.y;
  const int orig = blockIdx.y * gx + blockIdx.x;
  const int q8 = nwg >> 3, r8 = nwg & 7;
  const int xcd = orig & 7, loc = orig >> 3;
  const int swz = (xcd < r8) ? (xcd * (q8 + 1) + loc)
                             : (r8 * (q8 + 1) + (xcd - r8) * q8 + loc);
  const size_t m0 = (size_t)(swz / gx) * 256;
  const size_t n0 = (size_t)(swz % gx) * 256;
  const int NT = K / BK;

  // staging (r5 verbatim): thread tid covers granule tid of each 128-row
  // half; linear LDS dest = tid*16B; pre-inverse-swizzled global source
  // slot s = ((tid&3) - ((tid>>3)&3)) & 3.
  const int sgcol = (((tid & 3) - ((tid >> 3) & 3)) & 3) << 3;
  const ushort* a0 = A + (m0 + (tid >> 2)) * (size_t)K + sgcol;
  const ushort* b0 = Bt + (n0 + (tid >> 2)) * (size_t)K + sgcol;
  const size_t rowK = 128 * (size_t)K;
  ushort* ldst = &lds[tid * 8];

  // staging slot sl of tile t: 0 = A rows 0-127, 1 = A rows 128-255,
  // 2 = B rows 0-127, 3 = B rows 128-255 (one 16B gload each).
#define STAGE_SLOT(t, sl)                                                   \
  {                                                                         \
    ushort* d = ldst + ((t) & 3) * 16384 + (sl) * 4096;                     \
    const ushort* g = (((sl) < 2) ? a0 : b0) + (size_t)(t) * BK +           \
                      (((sl) & 1) ? rowK : 0);                              \
    GLD16(g, d);                                                            \
  }

  // reader (r5 verbatim): frag (row = base + lane&15, content slot
  // q = lane>>4) lives at slot' = (q + (row>>1)) & 3.
  const int cswz = ((((lane >> 4) + ((lane >> 1) & 3)) & 3) << 3);
  const int arow = wm * 128 + (lane & 15);
  const int brow = wn * 64 + (lane & 15);

  f32x4 acc[8][4] = {};

  // prologue: tiles 0,1,2 fully staged (12 loads)
#pragma unroll
  for (int pt = 0; pt < 3; ++pt) {
    STAGE_SLOT(pt, 0); STAGE_SLOT(pt, 1);
    STAGE_SLOT(pt, 2); STAGE_SLOT(pt, 3);
  }

  for (int t = 0; t < NT; ++t) {
    // tile t's 4 loads landed; keep tiles t+1,t+2 (8 loads) in flight
    if (t < NT - 2) {
      asm volatile("s_waitcnt vmcnt(8)" ::: "memory");
    } else if (t == NT - 2) {
      asm volatile("s_waitcnt vmcnt(4)" ::: "memory");
    } else {
      asm volatile("s_waitcnt vmcnt(0)" ::: "memory");
    }
    __builtin_amdgcn_s_barrier();

    const ushort* lA = &lds[(t & 3) * 16384];
    const ushort* lB = lA + 8192;

    // stage tile t+3 first (HBM latency hides under reads+MFMA below)
    if (t + 3 < NT) {
      STAGE_SLOT(t + 3, 0); STAGE_SLOT(t + 3, 1);
      STAGE_SLOT(t + 3, 2); STAGE_SLOT(t + 3, 3);
    }

    // all fragments; compiler schedules lgkmcnt finely, waves drift
    bf16x8 bfr[4], af[8];
#pragma unroll
    for (int ni = 0; ni < 4; ++ni)
      bfr[ni] = *(const bf16x8*)&lB[(brow + ni * 16) * 32 + cswz];
#pragma unroll
    for (int mi = 0; mi < 8; ++mi)
      af[mi] = *(const bf16x8*)&lA[(arow + mi * 16) * 32 + cswz];

    __builtin_amdgcn_s_setprio(1);
#pragma unroll
    for (int mi = 0; mi < 8; ++mi)
#pragma unroll
      for (int ni = 0; ni < 4; ++ni)
        acc[mi][ni] = __builtin_amdgcn_mfma_f32_16x16x32_bf16(
            af[mi], bfr[ni], acc[mi][ni], 0, 0, 0);
    __builtin_amdgcn_s_setprio(0);
  }
#undef STAGE_SLOT

  // epilogue: D col = lane&15, row = (lane>>4)*4 + j (m89-verified).
  // mi/j outer, ni inner (row's segments issued back-to-back).
  const int lm = lane & 15, lq = lane >> 4;
  size_t col[4];
  float bv[4];
#pragma unroll
  for (int ni = 0; ni < 4; ++ni) {
    col[ni] = n0 + wn * 64 + ni * 16 + lm;
    if (EPI == 0) {
      const float* bp = (n0 < 512) ? bias0 : ((n0 < 1024) ? bias1 : bias2);
      bv[ni] = bp[col[ni] & 511];
    } else {
      bv[ni] = bias0[col[ni]];
    }
  }
#pragma unroll
  for (int mi = 0; mi < 8; ++mi) {
#pragma unroll
    for (int j = 0; j < 4; ++j) {
      const size_t row = m0 + wm * 128 + mi * 16 + lq * 4 + j;
#pragma unroll
      for (int ni = 0; ni < 4; ++ni) {
        float v = acc[mi][ni][j] + bv[ni];
        if (EPI == 0) {
          ((ushort*)Cout)[row * N + col[ni]] = f2bf(v);
        } else if (EPI == 1) {
          ((ushort*)Cout)[row * N + col[ni]] = f2bf(fmaxf(v, 0.f));
        } else {
          v += bf2f(resid[row * N + col[ni]]);
          ((ushort*)Cout)[row * N + col[ni]] = f2bf(v);
        }
      }
    }
  }
}

// ---------------------------------------------------------------------------
// Per-token attention (H=8, HD=64) + residual + LN1 -> y (bf16)
// One wave per token; lane = head-dim element d. Residual from xb (bf16).
// Scores via 6-step transpose-reduce (63 shuffles); softmax in 8-lane groups;
// context via v_readlane broadcast.
// ---------------------------------------------------------------------------
__global__ __launch_bounds__(256) void attn_ln1(
    const ushort* __restrict__ qkv, const ushort* __restrict__ xb,
    const float* __restrict__ g1, const float* __restrict__ b1,
    ushort* __restrict__ y) {
  const int lane = threadIdx.x & 63;
  const size_t t = (size_t)blockIdx.x * 4 + (threadIdx.x >> 6);
  const ushort* base = qkv + t * 1536;
  float qd[8], kd[8], vd[8];
#pragma unroll
  for (int h = 0; h < 8; ++h) {
    qd[h] = bf2f(base[h * 64 + lane]);
    kd[h] = bf2f(base[512 + h * 64 + lane]);
    vd[h] = bf2f(base[1024 + h * 64 + lane]);
  }

  const bool lb0 = lane & 1, lb1 = lane & 2, lb2 = lane & 4;
  const bool lb3 = lane & 8, lb4 = lane & 16, lb5 = lane & 32;

  float c1[32];
#pragma unroll
  for (int f = 0; f < 32; ++f) {
    const int i0 = 2 * f, i1 = 2 * f + 1;
    const float a0 = qd[i0 >> 3] * kd[i0 & 7];
    const float a1 = qd[i1 >> 3] * kd[i1 & 7];
    const float keep = lb0 ? a1 : a0;
    const float send = lb0 ? a0 : a1;
    c1[f] = keep + __shfl_xor(send, 1, 64);
  }
  float c2[16];
#pragma unroll
  for (int f = 0; f < 16; ++f) {
    const float keep = lb1 ? c1[2 * f + 1] : c1[2 * f];
    const float send = lb1 ? c1[2 * f] : c1[2 * f + 1];
    c2[f] = keep + __shfl_xor(send, 2, 64);
  }
  float c3[8];
#pragma unroll
  for (int f = 0; f < 8; ++f) {
    const float keep = lb2 ? c2[2 * f + 1] : c2[2 * f];
    const float send = lb2 ? c2[2 * f] : c2[2 * f + 1];
    c3[f] = keep + __shfl_xor(send, 4, 64);
  }
  float c4[4];
#pragma unroll
  for (int f = 0; f < 4; ++f) {
    const float keep = lb3 ? c3[2 * f + 1] : c3[2 * f];
    const float send = lb3 ? c3[2 * f] : c3[2 * f + 1];
    c4[f] = keep + __shfl_xor(send, 8, 64);
  }
  float c5[2];
#pragma unroll
  for (int f = 0; f < 2; ++f) {
    const float keep = lb4 ? c4[2 * f + 1] : c4[2 * f];
    const float send = lb4 ? c4[2 * f] : c4[2 * f + 1];
    c5[f] = keep + __shfl_xor(send, 16, 64);
  }
  const float keep = lb5 ? c5[1] : c5[0];
  const float send = lb5 ? c5[0] : c5[1];
  const float s = keep + __shfl_xor(send, 32, 64);  // raw score, i = lane

  float mx = s;
  mx = fmaxf(mx, __shfl_xor(mx, 1, 64));
  mx = fmaxf(mx, __shfl_xor(mx, 2, 64));
  mx = fmaxf(mx, __shfl_xor(mx, 4, 64));
  const float e = __expf((s - mx) * 0.125f);
  float sum = e;
  sum += __shfl_xor(sum, 1, 64);
  sum += __shfl_xor(sum, 2, 64);
  sum += __shfl_xor(sum, 4, 64);
  const float a = e * __builtin_amdgcn_rcpf(sum);

  const int ai = __float_as_int(a);
  float r[8];
#pragma unroll
  for (int h = 0; h < 8; ++h) {
    float c = 0.f;
#pragma unroll
    for (int g = 0; g < 8; ++g) {
      const float w = __int_as_float(__builtin_amdgcn_readlane(ai, h * 8 + g));
      c = fmaf(w, vd[g], c);
    }
    r[h] = bf2f(xb[t * 512 + h * 64 + lane]) + c;
  }

  float sm = 0.f, sq = 0.f;
#pragma unroll
  for (int h = 0; h < 8; ++h) { sm += r[h]; sq += r[h] * r[h]; }
#pragma unroll
  for (int m = 1; m < 64; m <<= 1) {
    sm += __shfl_xor(sm, m, 64);
    sq += __shfl_xor(sq, m, 64);
  }
  const float mu = sm * (1.f / 512.f);
  const float var = sq * (1.f / 512.f) - mu * mu;
  const float rs = rsqrtf(var + 1e-5f);
#pragma unroll
  for (int h = 0; h < 8; ++h) {
    const int d = h * 64 + lane;
    y[t * 512 + d] = f2bf((r[h] - mu) * rs * g1[d] + b1[d]);
  }
}

// ---------------------------------------------------------------------------
// LN2(zb bf16) -> out fp32. One wave per token; lane owns 8 contiguous elems.
// ---------------------------------------------------------------------------
__global__ __launch_bounds__(256) void ln_out(
    const ushort* __restrict__ zb, const float* __restrict__ g2,
    const float* __restrict__ b2, float* __restrict__ out) {
  const int lane = threadIdx.x & 63;
  const size_t t = (size_t)blockIdx.x * 4 + (threadIdx.x >> 6);
  const u16x8 v = ((const u16x8*)(zb + t * 512))[lane];
  float r[8];
  float sm = 0.f, sq = 0.f;
#pragma unroll
  for (int j = 0; j < 8; ++j) {
    r[j] = bf2f(v[j]);
    sm += r[j];
    sq += r[j] * r[j];
  }
#pragma unroll
  for (int m = 1; m < 64; m <<= 1) {
    sm += __shfl_xor(sm, m, 64);
    sq += __shfl_xor(sq, m, 64);
  }
  const float mu = sm * (1.f / 512.f);
  const float rs = rsqrtf(sq * (1.f / 512.f) - mu * mu + 1e-5f);
  const int d0 = lane * 8;
  const float4 ga = *(const float4*)(g2 + d0);
  const float4 gb = *(const float4*)(g2 + d0 + 4);
  const float4 ba = *(const float4*)(b2 + d0);
  const float4 bb = *(const float4*)(b2 + d0 + 4);
  float4 oa, ob;
  oa.x = (r[0] - mu) * rs * ga.x + ba.x;
  oa.y = (r[1] - mu) * rs * ga.y + ba.y;
  oa.z = (r[2] - mu) * rs * ga.z + ba.z;
  oa.w = (r[3] - mu) * rs * ga.w + ba.w;
  ob.x = (r[4] - mu) * rs * gb.x + bb.x;
  ob.y = (r[5] - mu) * rs * gb.y + bb.y;
  ob.z = (r[6] - mu) * rs * gb.z + bb.z;
  ob.w = (r[7] - mu) * rs * gb.w + bb.w;
  float* o = out + t * 512 + d0;
  *(float4*)o = oa;
  *(float4*)(o + 4) = ob;
}

// ---------------------------------------------------------------------------
extern "C" void kernel_launch(void* const* d_in, const int* in_sizes, int n_in,
                              void* d_out, int out_size, void* d_ws,
                              size_t ws_size, hipStream_t stream) {
  const float* x    = (const float*)d_in[0];
  const float* Wq   = (const float*)d_in[1];
  const float* bq   = (const float*)d_in[2];
  const float* Wk   = (const float*)d_in[3];
  const float* bk   = (const float*)d_in[4];
  const float* Wv   = (const float*)d_in[5];
  const float* bv   = (const float*)d_in[6];
  const float* ln1g = (const float*)d_in[7];
  const float* ln1b = (const float*)d_in[8];
  const float* W1   = (const float*)d_in[9];
  const float* b1   = (const float*)d_in[10];
  const float* W2   = (const float*)d_in[11];
  const float* b2   = (const float*)d_in[12];
  const float* ln2g = (const float*)d_in[13];
  const float* ln2b = (const float*)d_in[14];
  float* out = (float*)d_out;

  const int Ntok = in_sizes[0] / 512;  // 65536

  // ---- workspace layout: weights once, then chunk buffers.
  // Per-token 6144 B via aliasing: region0 (4 KiB) = [xb 1K | qkv 3K]
  // before attn, reused as hb (4K) from FFN1 on; y 1K; zb 1K.
  char* ws = (char*)d_ws;
  ushort* Wqkvt = (ushort*)ws;                       // [1536][512]
  ushort* W1t   = Wqkvt + (size_t)1536 * 512;        // [2048][512]
  ushort* W2t   = W1t + (size_t)2048 * 512;          // [512][2048]
  const size_t woff = ((size_t)1536 * 512 + (size_t)2048 * 512 +
                       (size_t)512 * 2048) * 2;      // 5.5 MiB

  size_t avail = (ws_size > woff) ? (ws_size - woff) : 0;
  long long Cll = (long long)(avail / 6144);
  Cll = (Cll / 256) * 256;
  if (Cll > Ntok) Cll = Ntok;
  if (Cll < 256) Cll = 256;
  const int C = (int)Cll;

  char* cb = ws + woff;
  ushort* xb  = (ushort*)cb;                          // [C][512] bf16
  ushort* qkv = xb + (size_t)C * 512;                 // [C][1536] bf16
  ushort* hb  = (ushort*)cb;                          // [C][2048] (aliases xb|qkv)
  ushort* y   = (ushort*)cb + (size_t)C * 2048;       // [C][512] bf16
  ushort* zb  = y + (size_t)C * 512;                  // [C][512] bf16

  // ---- weight transposes (once)
  transpose_cast<<<dim3(16, 16), dim3(256), 0, stream>>>(Wq, Wqkvt, 512, 512, 0, 512);
  transpose_cast<<<dim3(16, 16), dim3(256), 0, stream>>>(Wk, Wqkvt, 512, 512, 512, 512);
  transpose_cast<<<dim3(16, 16), dim3(256), 0, stream>>>(Wv, Wqkvt, 512, 512, 1024, 512);
  transpose_cast<<<dim3(64, 16), dim3(256), 0, stream>>>(W1, W1t, 512, 2048, 0, 512);
  transpose_cast<<<dim3(16, 64), dim3(256), 0, stream>>>(W2, W2t, 2048, 512, 0, 2048);

  // ---- pipeline (single chunk when ws allows; C=65536 needs ~390 MiB)
  for (int t0 = 0; t0 < Ntok; t0 += C) {
    const int Cc = (Ntok - t0 < C) ? (Ntok - t0) : C;   // multiple of 256
    const float* xc = x + (size_t)t0 * 512;

    cast_f32_bf16<<<dim3((Cc * 512) / 2048), dim3(256), 0, stream>>>(xc, xb);

    gemm_bt<0><<<dim3(1536 / 256, Cc / 256), dim3(512), 0, stream>>>(
        xb, Wqkvt, 1536, 512, qkv, bq, bk, bv, nullptr);

    attn_ln1<<<dim3(Cc / 4), dim3(256), 0, stream>>>(qkv, xb, ln1g, ln1b, y);

    // hb overwrites [xb|qkv] — both dead after attn_ln1
    gemm_bt<1><<<dim3(2048 / 256, Cc / 256), dim3(512), 0, stream>>>(
        y, W1t, 2048, 512, hb, b1, nullptr, nullptr, nullptr);

    gemm_bt<2><<<dim3(512 / 256, Cc / 256), dim3(512), 0, stream>>>(
        hb, W2t, 512, 2048, zb, b2, nullptr, nullptr, y);

    ln_out<<<dim3(Cc / 4), dim3(256), 0, stream>>>(
        zb, ln2g, ln2b, out + (size_t)t0 * 512);
  }
}

// Round 15
// 629.195 us; speedup vs baseline: 1.0429x; 1.0328x over previous
//
#include <hip/hip_runtime.h>
#include <cstdint>

// ---------------------------------------------------------------------------
// TransformerLayer on MI355X (gfx950)
// Chunked pipeline (chunk C tokens, per-token ws = 9 KiB):
//   once: transpose-cast weights -> bf16 [N][K]
//   per chunk:
//     1. cast x -> bf16 (xb)
//     2. GEMM qkv = xb @ [Wq|Wk|Wv] + bias          (bf16 out, EPI=0, NB=2)
//     3. attn (per-token 8x8) + residual + LN1 -> y (bf16)
//     4. GEMM h = relu(y @ W1 + b1)                 (bf16 out, EPI=1, NB=2)
//     5. GEMM zb = h @ W2 + b2 + y                  (bf16 out, EPI=2, NB=4)
//     6. LN2(zb) -> out (fp32)
// GEMM (r15): r10 skeleton with per-GEMM buffer policy NB:
//   NB=2 (64 KiB LDS, stage t+1, vmcnt(0)/tile): 2 blocks/CU -- for QKV/FFN1
//     whose grids (768/1024) give every CU a second block to cover the
//     depth-1 prefetch stall (r13 evidence: FFN1 dropped below top-5).
//   NB=4 (128 KiB, stage t+3, counted vmcnt(8)): deep prefetch -- for FFN2
//     whose 256-block grid can never get a second block/CU (r13 evidence:
//     FFN2 regressed to 98 us under NB=2).
// Shared pieces (r5-proven): 256x256 tile, BK=32, 8 waves, 0-conflict
// additive LDS swizzle, XCD-bijective block swizzle, setprio, one
// barrier/tile, 16x16x32 MFMA with m89-verified layouts.
// ---------------------------------------------------------------------------

typedef __attribute__((ext_vector_type(8))) short bf16x8;
typedef __attribute__((ext_vector_type(4))) float f32x4;
typedef __attribute__((ext_vector_type(8))) unsigned short u16x8;

__device__ __forceinline__ float bf2f(unsigned short u) {
  union { unsigned int i; float f; } v; v.i = ((unsigned int)u) << 16; return v.f;
}
__device__ __forceinline__ unsigned short f2bf(float f) {
  union { float f; unsigned int i; } v; v.f = f;
  unsigned int r = v.i + 0x7FFFu + ((v.i >> 16) & 1u);   // round-nearest-even
  return (unsigned short)(r >> 16);
}

#define GLD16(g, l)                                                         \
  __builtin_amdgcn_global_load_lds(                                         \
      (const __attribute__((address_space(1))) void*)(g),                   \
      (__attribute__((address_space(3))) void*)(l), 16, 0, 0)

// ---------------------------------------------------------------------------
// fp32 -> bf16 cast, 8 elements/thread, vectorized
// ---------------------------------------------------------------------------
__global__ __launch_bounds__(256) void cast_f32_bf16(
    const float* __restrict__ in, ushort* __restrict__ out) {
  const size_t i = (size_t)blockIdx.x * 256 + threadIdx.x;
  const float4* p = (const float4*)in + i * 2;
  float4 a = p[0], b = p[1];
  u16x8 r;
  r[0] = f2bf(a.x); r[1] = f2bf(a.y); r[2] = f2bf(a.z); r[3] = f2bf(a.w);
  r[4] = f2bf(b.x); r[5] = f2bf(b.y); r[6] = f2bf(b.z); r[7] = f2bf(b.w);
  ((u16x8*)out)[i] = r;
}

// ---------------------------------------------------------------------------
// Transpose-cast: W fp32 [K][Nn] row-major -> Wt bf16 [rowoff+Nn][ldt=K]
// ---------------------------------------------------------------------------
__global__ __launch_bounds__(256) void transpose_cast(
    const float* __restrict__ W, ushort* __restrict__ Wt,
    int K, int Nn, int rowoff, int ldt) {
  __shared__ float tile[32][33];
  const int tx = threadIdx.x & 31, ty = threadIdx.x >> 5;  // ty: 0..7
  const int nb = blockIdx.x * 32, kb = blockIdx.y * 32;
#pragma unroll
  for (int s = 0; s < 4; ++s)
    tile[ty + 8 * s][tx] = W[(size_t)(kb + ty + 8 * s) * Nn + nb + tx];
  __syncthreads();
#pragma unroll
  for (int s = 0; s < 4; ++s)
    Wt[(size_t)(rowoff + nb + ty + 8 * s) * ldt + kb + tx] =
        f2bf(tile[tx][ty + 8 * s]);
}

// ---------------------------------------------------------------------------
// bf16 GEMM, C = A[M,K] @ Bt[N,K]^T
// 256x256 tile, BK=32, 8 waves (2M x 4N), per-wave out 128x64 (8x4 frags).
// NB-buffered LDS (NB=2: stage t+1, drain vmcnt(0); NB=4: stage t+3,
// counted vmcnt(8)). One barrier/tile; waves drift for LDS<->MFMA overlap.
// LDS swizzle (r5-proven 0 conflicts): content slot q at row r lives at
// dest slot (q + (r>>1)) & 3; staging source slot = ((tid&3)-((tid>>3)&3))&3.
// EPI 0: +bias(select by n0), bf16 out   (QKV)
// EPI 1: relu(+bias), bf16 out           (FFN1)
// EPI 2: +bias +resid(bf16), bf16 out    (FFN2 -> zb)
// ---------------------------------------------------------------------------
template <int EPI, int NB>
__global__ __launch_bounds__(512, 2) void gemm_bt(
    const ushort* __restrict__ A, const ushort* __restrict__ Bt,
    int N, int K, void* __restrict__ Cout,
    const float* __restrict__ bias0, const float* __restrict__ bias1,
    const float* __restrict__ bias2, const ushort* __restrict__ resid) {
  constexpr int BK = 32;
  __shared__ __align__(16) ushort lds[NB * 16384];
  const int tid = threadIdx.x;
  const int wid = tid >> 6, lane = tid & 63;
  const int wm = wid >> 2, wn = wid & 3;

  // ---- XCD-aware bijective block swizzle (m204)
  const int gx = gridDim.x;
  const int nwg = gx * gridDim.y;
  const int orig = blockIdx.y * gx + blockIdx.x;
  const int q8 = nwg >> 3, r8 = nwg & 7;
  const int xcd = orig & 7, loc = orig >> 3;
  const int swz = (xcd < r8) ? (xcd * (q8 + 1) + loc)
                             : (r8 * (q8 + 1) + (xcd - r8) * q8 + loc);
  const size_t m0 = (size_t)(swz / gx) * 256;
  const size_t n0 = (size_t)(swz % gx) * 256;
  const int NT = K / BK;

  // staging (r5 verbatim): thread tid covers granule tid of each 128-row
  // half; linear LDS dest = tid*16B; pre-inverse-swizzled global source
  // slot s = ((tid&3) - ((tid>>3)&3)) & 3.
  const int sgcol = (((tid & 3) - ((tid >> 3) & 3)) & 3) << 3;
  const ushort* a0 = A + (m0 + (tid >> 2)) * (size_t)K + sgcol;
  const ushort* b0 = Bt + (n0 + (tid >> 2)) * (size_t)K + sgcol;
  const size_t rowK = 128 * (size_t)K;
  ushort* ldst = &lds[tid * 8];

  // staging slot sl of tile t: 0 = A rows 0-127, 1 = A rows 128-255,
  // 2 = B rows 0-127, 3 = B rows 128-255 (one 16B gload each).
#define STAGE_SLOT(t, sl)                                                   \
  {                                                                         \
    ushort* d = ldst + ((t) & (NB - 1)) * 16384 + (sl) * 4096;              \
    const ushort* g = (((sl) < 2) ? a0 : b0) + (size_t)(t) * BK +           \
                      (((sl) & 1) ? rowK : 0);                              \
    GLD16(g, d);                                                            \
  }

  // reader (r5 verbatim): frag (row = base + lane&15, content slot
  // q = lane>>4) lives at slot' = (q + (row>>1)) & 3.
  const int cswz = ((((lane >> 4) + ((lane >> 1) & 3)) & 3) << 3);
  const int arow = wm * 128 + (lane & 15);
  const int brow = wn * 64 + (lane & 15);

  f32x4 acc[8][4] = {};

  // prologue
  if constexpr (NB == 4) {
#pragma unroll
    for (int pt = 0; pt < 3; ++pt) {
      STAGE_SLOT(pt, 0); STAGE_SLOT(pt, 1);
      STAGE_SLOT(pt, 2); STAGE_SLOT(pt, 3);
    }
  } else {
    STAGE_SLOT(0, 0); STAGE_SLOT(0, 1);
    STAGE_SLOT(0, 2); STAGE_SLOT(0, 3);
  }

  for (int t = 0; t < NT; ++t) {
    if constexpr (NB == 4) {
      // tile t's 4 loads landed; keep tiles t+1,t+2 (8 loads) in flight
      if (t < NT - 2) {
        asm volatile("s_waitcnt vmcnt(8)" ::: "memory");
      } else if (t == NT - 2) {
        asm volatile("s_waitcnt vmcnt(4)" ::: "memory");
      } else {
        asm volatile("s_waitcnt vmcnt(0)" ::: "memory");
      }
    } else {
      // tile t's 4 loads (issued one full tile-compute ago) must be done
      asm volatile("s_waitcnt vmcnt(0)" ::: "memory");
    }
    __builtin_amdgcn_s_barrier();

    const ushort* lA = &lds[(t & (NB - 1)) * 16384];
    const ushort* lB = lA + 8192;

    // stage the next prefetch target (buffer's readers finished before
    // this barrier); HBM latency hides under this tile's reads+MFMA.
    if constexpr (NB == 4) {
      if (t + 3 < NT) {
        STAGE_SLOT(t + 3, 0); STAGE_SLOT(t + 3, 1);
        STAGE_SLOT(t + 3, 2); STAGE_SLOT(t + 3, 3);
      }
    } else {
      if (t + 1 < NT) {
        STAGE_SLOT(t + 1, 0); STAGE_SLOT(t + 1, 1);
        STAGE_SLOT(t + 1, 2); STAGE_SLOT(t + 1, 3);
      }
    }

    // all fragments; compiler schedules lgkmcnt finely, waves drift
    bf16x8 bfr[4], af[8];
#pragma unroll
    for (int ni = 0; ni < 4; ++ni)
      bfr[ni] = *(const bf16x8*)&lB[(brow + ni * 16) * 32 + cswz];
#pragma unroll
    for (int mi = 0; mi < 8; ++mi)
      af[mi] = *(const bf16x8*)&lA[(arow + mi * 16) * 32 + cswz];

    __builtin_amdgcn_s_setprio(1);
#pragma unroll
    for (int mi = 0; mi < 8; ++mi)
#pragma unroll
      for (int ni = 0; ni < 4; ++ni)
        acc[mi][ni] = __builtin_amdgcn_mfma_f32_16x16x32_bf16(
            af[mi], bfr[ni], acc[mi][ni], 0, 0, 0);
    __builtin_amdgcn_s_setprio(0);
  }
#undef STAGE_SLOT

  // epilogue: D col = lane&15, row = (lane>>4)*4 + j (m89-verified).
  // mi/j outer, ni inner (row's segments issued back-to-back).
  const int lm = lane & 15, lq = lane >> 4;
  size_t col[4];
  float bv[4];
#pragma unroll
  for (int ni = 0; ni < 4; ++ni) {
    col[ni] = n0 + wn * 64 + ni * 16 + lm;
    if (EPI == 0) {
      const float* bp = (n0 < 512) ? bias0 : ((n0 < 1024) ? bias1 : bias2);
      bv[ni] = bp[col[ni] & 511];
    } else {
      bv[ni] = bias0[col[ni]];
    }
  }
#pragma unroll
  for (int mi = 0; mi < 8; ++mi) {
#pragma unroll
    for (int j = 0; j < 4; ++j) {
      const size_t row = m0 + wm * 128 + mi * 16 + lq * 4 + j;
#pragma unroll
      for (int ni = 0; ni < 4; ++ni) {
        float v = acc[mi][ni][j] + bv[ni];
        if (EPI == 0) {
          ((ushort*)Cout)[row * N + col[ni]] = f2bf(v);
        } else if (EPI == 1) {
          ((ushort*)Cout)[row * N + col[ni]] = f2bf(fmaxf(v, 0.f));
        } else {
          v += bf2f(resid[row * N + col[ni]]);
          ((ushort*)Cout)[row * N + col[ni]] = f2bf(v);
        }
      }
    }
  }
}

// ---------------------------------------------------------------------------
// Per-token attention (H=8, HD=64) + residual + LN1 -> y (bf16)
// One wave per token; lane = head-dim element d. Residual from xb (bf16).
// Scores via 6-step transpose-reduce (63 shuffles); softmax in 8-lane groups;
// context via v_readlane broadcast.
// ---------------------------------------------------------------------------
__global__ __launch_bounds__(256) void attn_ln1(
    const ushort* __restrict__ qkv, const ushort* __restrict__ xb,
    const float* __restrict__ g1, const float* __restrict__ b1,
    ushort* __restrict__ y) {
  const int lane = threadIdx.x & 63;
  const size_t t = (size_t)blockIdx.x * 4 + (threadIdx.x >> 6);
  const ushort* base = qkv + t * 1536;
  float qd[8], kd[8], vd[8];
#pragma unroll
  for (int h = 0; h < 8; ++h) {
    qd[h] = bf2f(base[h * 64 + lane]);
    kd[h] = bf2f(base[512 + h * 64 + lane]);
    vd[h] = bf2f(base[1024 + h * 64 + lane]);
  }

  const bool lb0 = lane & 1, lb1 = lane & 2, lb2 = lane & 4;
  const bool lb3 = lane & 8, lb4 = lane & 16, lb5 = lane & 32;

  float c1[32];
#pragma unroll
  for (int f = 0; f < 32; ++f) {
    const int i0 = 2 * f, i1 = 2 * f + 1;
    const float a0 = qd[i0 >> 3] * kd[i0 & 7];
    const float a1 = qd[i1 >> 3] * kd[i1 & 7];
    const float keep = lb0 ? a1 : a0;
    const float send = lb0 ? a0 : a1;
    c1[f] = keep + __shfl_xor(send, 1, 64);
  }
  float c2[16];
#pragma unroll
  for (int f = 0; f < 16; ++f) {
    const float keep = lb1 ? c1[2 * f + 1] : c1[2 * f];
    const float send = lb1 ? c1[2 * f] : c1[2 * f + 1];
    c2[f] = keep + __shfl_xor(send, 2, 64);
  }
  float c3[8];
#pragma unroll
  for (int f = 0; f < 8; ++f) {
    const float keep = lb2 ? c2[2 * f + 1] : c2[2 * f];
    const float send = lb2 ? c2[2 * f] : c2[2 * f + 1];
    c3[f] = keep + __shfl_xor(send, 4, 64);
  }
  float c4[4];
#pragma unroll
  for (int f = 0; f < 4; ++f) {
    const float keep = lb3 ? c3[2 * f + 1] : c3[2 * f];
    const float send = lb3 ? c3[2 * f] : c3[2 * f + 1];
    c4[f] = keep + __shfl_xor(send, 8, 64);
  }
  float c5[2];
#pragma unroll
  for (int f = 0; f < 2; ++f) {
    const float keep = lb4 ? c4[2 * f + 1] : c4[2 * f];
    const float send = lb4 ? c4[2 * f] : c4[2 * f + 1];
    c5[f] = keep + __shfl_xor(send, 16, 64);
  }
  const float keep = lb5 ? c5[1] : c5[0];
  const float send = lb5 ? c5[0] : c5[1];
  const float s = keep + __shfl_xor(send, 32, 64);  // raw score, i = lane

  float mx = s;
  mx = fmaxf(mx, __shfl_xor(mx, 1, 64));
  mx = fmaxf(mx, __shfl_xor(mx, 2, 64));
  mx = fmaxf(mx, __shfl_xor(mx, 4, 64));
  const float e = __expf((s - mx) * 0.125f);
  float sum = e;
  sum += __shfl_xor(sum, 1, 64);
  sum += __shfl_xor(sum, 2, 64);
  sum += __shfl_xor(sum, 4, 64);
  const float a = e * __builtin_amdgcn_rcpf(sum);

  const int ai = __float_as_int(a);
  float r[8];
#pragma unroll
  for (int h = 0; h < 8; ++h) {
    float c = 0.f;
#pragma unroll
    for (int g = 0; g < 8; ++g) {
      const float w = __int_as_float(__builtin_amdgcn_readlane(ai, h * 8 + g));
      c = fmaf(w, vd[g], c);
    }
    r[h] = bf2f(xb[t * 512 + h * 64 + lane]) + c;
  }

  float sm = 0.f, sq = 0.f;
#pragma unroll
  for (int h = 0; h < 8; ++h) { sm += r[h]; sq += r[h] * r[h]; }
#pragma unroll
  for (int m = 1; m < 64; m <<= 1) {
    sm += __shfl_xor(sm, m, 64);
    sq += __shfl_xor(sq, m, 64);
  }
  const float mu = sm * (1.f / 512.f);
  const float var = sq * (1.f / 512.f) - mu * mu;
  const float rs = rsqrtf(var + 1e-5f);
#pragma unroll
  for (int h = 0; h < 8; ++h) {
    const int d = h * 64 + lane;
    y[t * 512 + d] = f2bf((r[h] - mu) * rs * g1[d] + b1[d]);
  }
}

// ---------------------------------------------------------------------------
// LN2(zb bf16) -> out fp32. One wave per token; lane owns 8 contiguous elems.
// ---------------------------------------------------------------------------
__global__ __launch_bounds__(256) void ln_out(
    const ushort* __restrict__ zb, const float* __restrict__ g2,
    const float* __restrict__ b2, float* __restrict__ out) {
  const int lane = threadIdx.x & 63;
  const size_t t = (size_t)blockIdx.x * 4 + (threadIdx.x >> 6);
  const u16x8 v = ((const u16x8*)(zb + t * 512))[lane];
  float r[8];
  float sm = 0.f, sq = 0.f;
#pragma unroll
  for (int j = 0; j < 8; ++j) {
    r[j] = bf2f(v[j]);
    sm += r[j];
    sq += r[j] * r[j];
  }
#pragma unroll
  for (int m = 1; m < 64; m <<= 1) {
    sm += __shfl_xor(sm, m, 64);
    sq += __shfl_xor(sq, m, 64);
  }
  const float mu = sm * (1.f / 512.f);
  const float rs = rsqrtf(sq * (1.f / 512.f) - mu * mu + 1e-5f);
  const int d0 = lane * 8;
  const float4 ga = *(const float4*)(g2 + d0);
  const float4 gb = *(const float4*)(g2 + d0 + 4);
  const float4 ba = *(const float4*)(b2 + d0);
  const float4 bb = *(const float4*)(b2 + d0 + 4);
  float4 oa, ob;
  oa.x = (r[0] - mu) * rs * ga.x + ba.x;
  oa.y = (r[1] - mu) * rs * ga.y + ba.y;
  oa.z = (r[2] - mu) * rs * ga.z + ba.z;
  oa.w = (r[3] - mu) * rs * ga.w + ba.w;
  ob.x = (r[4] - mu) * rs * gb.x + bb.x;
  ob.y = (r[5] - mu) * rs * gb.y + bb.y;
  ob.z = (r[6] - mu) * rs * gb.z + bb.z;
  ob.w = (r[7] - mu) * rs * gb.w + bb.w;
  float* o = out + t * 512 + d0;
  *(float4*)o = oa;
  *(float4*)(o + 4) = ob;
}

// ---------------------------------------------------------------------------
extern "C" void kernel_launch(void* const* d_in, const int* in_sizes, int n_in,
                              void* d_out, int out_size, void* d_ws,
                              size_t ws_size, hipStream_t stream) {
  const float* x    = (const float*)d_in[0];
  const float* Wq   = (const float*)d_in[1];
  const float* bq   = (const float*)d_in[2];
  const float* Wk   = (const float*)d_in[3];
  const float* bk   = (const float*)d_in[4];
  const float* Wv   = (const float*)d_in[5];
  const float* bv   = (const float*)d_in[6];
  const float* ln1g = (const float*)d_in[7];
  const float* ln1b = (const float*)d_in[8];
  const float* W1   = (const float*)d_in[9];
  const float* b1   = (const float*)d_in[10];
  const float* W2   = (const float*)d_in[11];
  const float* b2   = (const float*)d_in[12];
  const float* ln2g = (const float*)d_in[13];
  const float* ln2b = (const float*)d_in[14];
  float* out = (float*)d_out;

  const int Ntok = in_sizes[0] / 512;  // 65536

  // ---- workspace layout: weights once, then chunk buffers (9 KiB/token)
  char* ws = (char*)d_ws;
  ushort* Wqkvt = (ushort*)ws;                       // [1536][512]
  ushort* W1t   = Wqkvt + (size_t)1536 * 512;        // [2048][512]
  ushort* W2t   = W1t + (size_t)2048 * 512;          // [512][2048]
  const size_t woff = ((size_t)1536 * 512 + (size_t)2048 * 512 +
                       (size_t)512 * 2048) * 2;      // 5.5 MiB

  size_t avail = (ws_size > woff) ? (ws_size - woff) : 0;
  long long Cll = (long long)(avail / 9216);
  Cll = (Cll / 256) * 256;
  if (Cll > 32768) Cll = 32768;
  if (Cll > Ntok) Cll = Ntok;
  if (Cll < 256) Cll = 256;
  const int C = (int)Cll;

  char* cb = ws + woff;
  ushort* xb  = (ushort*)cb;                          // [C][512] bf16
  ushort* y   = xb + (size_t)C * 512;                 // [C][512] bf16
  ushort* qkv = y + (size_t)C * 512;                  // [C][1536] bf16
  ushort* hb  = qkv + (size_t)C * 1536;               // [C][2048] bf16
  ushort* zb  = qkv;                                  // [C][512] bf16 (aliases qkv)

  // ---- weight transposes (once)
  transpose_cast<<<dim3(16, 16), dim3(256), 0, stream>>>(Wq, Wqkvt, 512, 512, 0, 512);
  transpose_cast<<<dim3(16, 16), dim3(256), 0, stream>>>(Wk, Wqkvt, 512, 512, 512, 512);
  transpose_cast<<<dim3(16, 16), dim3(256), 0, stream>>>(Wv, Wqkvt, 512, 512, 1024, 512);
  transpose_cast<<<dim3(64, 16), dim3(256), 0, stream>>>(W1, W1t, 512, 2048, 0, 512);
  transpose_cast<<<dim3(16, 64), dim3(256), 0, stream>>>(W2, W2t, 2048, 512, 0, 2048);

  // ---- chunked pipeline
  for (int t0 = 0; t0 < Ntok; t0 += C) {
    const int Cc = (Ntok - t0 < C) ? (Ntok - t0) : C;   // multiple of 256
    const float* xc = x + (size_t)t0 * 512;

    cast_f32_bf16<<<dim3((Cc * 512) / 2048), dim3(256), 0, stream>>>(xc, xb);

    gemm_bt<0, 2><<<dim3(1536 / 256, Cc / 256), dim3(512), 0, stream>>>(
        xb, Wqkvt, 1536, 512, qkv, bq, bk, bv, nullptr);

    attn_ln1<<<dim3(Cc / 4), dim3(256), 0, stream>>>(qkv, xb, ln1g, ln1b, y);

    gemm_bt<1, 2><<<dim3(2048 / 256, Cc / 256), dim3(512), 0, stream>>>(
        y, W1t, 2048, 512, hb, b1, nullptr, nullptr, nullptr);

    gemm_bt<2, 4><<<dim3(512 / 256, Cc / 256), dim3(512), 0, stream>>>(
        hb, W2t, 512, 2048, zb, b2, nullptr, nullptr, y);

    ln_out<<<dim3(Cc / 4), dim3(256), 0, stream>>>(
        zb, ln2g, ln2b, out + (size_t)t0 * 512);
  }
}